// Round 7
// baseline (414.971 us; speedup 1.0000x reference)
//
#include <hip/hip_runtime.h>

typedef unsigned short u16;
typedef unsigned int u32;
typedef __attribute__((ext_vector_type(8))) short bf16x8;
typedef __attribute__((ext_vector_type(4))) float f32x4;

__device__ __forceinline__ u16 f2bf(float f) {
  union { float f; unsigned int u; } x;
  x.f = f;
  unsigned int r = x.u + 0x7fffu + ((x.u >> 16) & 1u);
  return (u16)(r >> 16);
}

__device__ __forceinline__ float bf2f(u16 v) {
  union { unsigned int u; float f; } x;
  x.u = ((unsigned int)v) << 16;
  return x.f;
}

__device__ __forceinline__ u32 fbits(float f) {
  union { float f; u32 u; } x; x.f = f; return x.u;
}

__device__ __forceinline__ void async16(const u16* g, u16* l) {
  __builtin_amdgcn_global_load_lds((const __attribute__((address_space(1))) void*)g,
                                   (__attribute__((address_space(3))) void*)l, 16, 0, 0);
}

// Stage 128 rows x 64 cols bf16 tile. LDS slot s: row=s>>3, stored chunk (s&7)
// holds global 16B chunk c = (s&7) ^ (row&7)  (XOR swizzle -> conflict-free b128 reads).
__device__ __forceinline__ void stage128x64(const u16* __restrict__ src, long row0, int k0,
                                            int ld, u16* lds, int wave, int lane) {
#pragma unroll
  for (int r = 0; r < 4; ++r) {
    int s = r * 256 + wave * 64 + lane;
    int row = s >> 3;
    int c = (s & 7) ^ (row & 7);
    async16(src + (row0 + row) * (long)ld + k0 + c * 8, lds + (r * 256 + wave * 64) * 8);
  }
}

// Stage 64 rows x 128 cols (V^T tile): 16 chunks/row, swizzle c = (s&15)^(row&15).
__device__ __forceinline__ void stage64x128(const u16* __restrict__ src, int col0, int ld,
                                            u16* lds, int wave, int lane) {
#pragma unroll
  for (int r = 0; r < 4; ++r) {
    int s = r * 256 + wave * 64 + lane;
    int row = s >> 4;
    int c = (s & 15) ^ (row & 15);
    async16(src + (long)row * ld + col0 + c * 8, lds + (r * 256 + wave * 64) * 8);
  }
}

// ---------------- LayerNorm core (torch-style: unbiased std, /(std+eps)) ----------------
__device__ __forceinline__ void ln_core(float4 v, const float* g, const float* b, int t,
                                        u16* outrow) {
  float s = v.x + v.y + v.z + v.w;
  float ss = v.x * v.x + v.y * v.y + v.z * v.z + v.w * v.w;
#pragma unroll
  for (int off = 32; off; off >>= 1) {
    s += __shfl_xor(s, off);
    ss += __shfl_xor(ss, off);
  }
  __shared__ float red[8];
  int wave = t >> 6, lane = t & 63;
  if (lane == 0) { red[wave] = s; red[wave + 4] = ss; }
  __syncthreads();
  float tot = red[0] + red[1] + red[2] + red[3];
  float tots = red[4] + red[5] + red[6] + red[7];
  float mean = tot * (1.0f / 1024.0f);
  float var = (tots - 1024.0f * mean * mean) * (1.0f / 1023.0f);
  var = fmaxf(var, 0.0f);
  float inv = 1.0f / (sqrtf(var) + 1e-6f);
  float4 gv = ((const float4*)g)[t];
  float4 bv = ((const float4*)b)[t];
  union { unsigned long long u64; u16 h[4]; } o;
  o.h[0] = f2bf(gv.x * (v.x - mean) * inv + bv.x);
  o.h[1] = f2bf(gv.y * (v.y - mean) * inv + bv.y);
  o.h[2] = f2bf(gv.z * (v.z - mean) * inv + bv.z);
  o.h[3] = f2bf(gv.w * (v.w - mean) * inv + bv.w);
  *(unsigned long long*)(outrow + t * 4) = o.u64;
}

// ---------------- prep: all weight transposes + LN1 in ONE launch ----------------
// 16384 blocks: [0,4k) wq/wk/wv/wo transpose; [4k,8k) LN1; [8k,12k) w1; [12k,16k) w2.
__global__ __launch_bounds__(256) void prep(const float* __restrict__ wq,
                                            const float* __restrict__ wk,
                                            const float* __restrict__ wv,
                                            const float* __restrict__ wo,
                                            const float* __restrict__ w1,
                                            const float* __restrict__ w2,
                                            const float* __restrict__ x,
                                            const float* __restrict__ ln1_g,
                                            const float* __restrict__ ln1_b,
                                            u16* __restrict__ wqkvT,  // + woT contiguous
                                            u16* __restrict__ w1T,
                                            u16* __restrict__ w2T,
                                            u16* __restrict__ hout) {
  const int bid = blockIdx.x;
  const int part = bid >> 12;
  const int local = bid & 4095;
  const int t = threadIdx.x;
  if (part == 1) {
    float4 v = ((const float4*)(x + (long)local * 1024))[t];
    ln_core(v, ln1_g, ln1_b, t, hout + (long)local * 1024);
    return;
  }
  __shared__ float tile[32][33];
  const float* src; u16* dst; int C, R, bx, by;
  if (part == 0) {
    int sub = local >> 10;
    src = sub == 0 ? wq : (sub == 1 ? wk : (sub == 2 ? wv : wo));
    dst = wqkvT + (long)sub * 1024 * 1024;
    C = 1024; R = 1024; bx = local & 31; by = (local >> 5) & 31;
  } else if (part == 2) {
    src = w1; dst = w1T; C = 4096; R = 1024; bx = local & 127; by = local >> 7;
  } else {
    src = w2; dst = w2T; C = 1024; R = 4096; bx = local & 31; by = local >> 5;
  }
  int c0 = bx * 32, r0 = by * 32;
  int tx = t & 31, ty = t >> 5;
#pragma unroll
  for (int i = 0; i < 32; i += 8)
    tile[ty + i][tx] = src[(long)(r0 + ty + i) * C + c0 + tx];
  __syncthreads();
#pragma unroll
  for (int i = 0; i < 32; i += 8)
    dst[(long)(c0 + ty + i) * R + r0 + tx] = f2bf(tile[tx][ty + i]);
}

// y = x + bres + P0 + P1 (WO split-K2 reduce); write y fp32 and LN2(y) bf16.
__global__ __launch_bounds__(256) void ln_fuse(const float* __restrict__ x,
                                               const float* __restrict__ bres,
                                               const u16* __restrict__ p0,
                                               const u16* __restrict__ p1,
                                               const float* __restrict__ g,
                                               const float* __restrict__ b,
                                               float* __restrict__ yout,
                                               u16* __restrict__ hout) {
  int row = blockIdx.x, t = threadIdx.x;
  long base = (long)row * 1024;
  float4 xv = ((const float4*)(x + base))[t];
  float4 bo = ((const float4*)bres)[t];
  ushort4 a = ((const ushort4*)(p0 + base))[t];
  ushort4 c = ((const ushort4*)(p1 + base))[t];
  float4 y;
  y.x = xv.x + bo.x + bf2f(a.x) + bf2f(c.x);
  y.y = xv.y + bo.y + bf2f(a.y) + bf2f(c.y);
  y.z = xv.z + bo.z + bf2f(a.z) + bf2f(c.z);
  y.w = xv.w + bo.w + bf2f(a.w) + bf2f(c.w);
  ((float4*)(yout + base))[t] = y;
  ln_core(y, g, b, t, hout + base);
}

// out += b2 + Q0 + Q1 (FFN2 split-K2 reduce + bias, in-place on residual)
__global__ __launch_bounds__(256) void final_add(float* __restrict__ out,
                                                 const float* __restrict__ b2,
                                                 const u16* __restrict__ p0,
                                                 const u16* __restrict__ p1) {
  int row = blockIdx.x, t = threadIdx.x;
  long base = (long)row * 1024;
  float4 o = ((float4*)(out + base))[t];
  float4 bb = ((const float4*)b2)[t];
  ushort4 a = ((const ushort4*)(p0 + base))[t];
  ushort4 c = ((const ushort4*)(p1 + base))[t];
  o.x += bb.x + bf2f(a.x) + bf2f(c.x);
  o.y += bb.y + bf2f(a.y) + bf2f(c.y);
  o.z += bb.z + bf2f(a.z) + bf2f(c.z);
  o.w += bb.w + bf2f(a.w) + bf2f(c.w);
  ((float4*)(out + base))[t] = o;
}

// ---------------- bf16 GEMM: C = A(MxK) @ Bt(NxK)^T, templated epilogue ----------------
// MODE 0: QKV scatter (+bias; q *= 0.125*log2e; q/k direct, v via LDS transpose -> (bh,d,s))
// MODE 1: bf16 partial store; pointer per z: z0->outp, z1->q_out
// MODE 2: out bf16 = relu(acc + bias0)
template <int MODE>
__global__ __launch_bounds__(256) void gemm_bt(const u16* __restrict__ A,
                                               const u16* __restrict__ Bt, int M, int N, int K,
                                               void* __restrict__ outp,
                                               const float* __restrict__ bias0,
                                               const float* __restrict__ bias1,
                                               const float* __restrict__ bias2,
                                               u16* __restrict__ q_out, u16* __restrict__ k_out,
                                               u16* __restrict__ v_out) {
  __shared__ __align__(16) u16 lds[17408];  // A: [0,8192) B: [8192,16384); epi: 128x136
  u16* ldsA = lds;
  u16* ldsB = lds + 8192;
  const int tid = threadIdx.x;
  const int wave = tid >> 6, lane = tid & 63;
  const int lane16 = lane & 15, quad = lane >> 4;
  const int wm = (wave >> 1) * 64, wn = (wave & 1) * 64;
  const long m0 = (long)blockIdx.y * 128;
  const long n0 = (long)blockIdx.x * 128;
  const int kLen = K / gridDim.z;
  const int kBeg = blockIdx.z * kLen;

  const f32x4 fzero = {0.f, 0.f, 0.f, 0.f};
  f32x4 acc[4][4];
#pragma unroll
  for (int i = 0; i < 4; ++i)
#pragma unroll
    for (int j = 0; j < 4; ++j) acc[i][j] = fzero;

  for (int k0 = kBeg; k0 < kBeg + kLen; k0 += 64) {
    stage128x64(A, m0, k0, K, ldsA, wave, lane);
    stage128x64(Bt, n0, k0, K, ldsB, wave, lane);
    __syncthreads();
#pragma unroll
    for (int kk = 0; kk < 2; ++kk) {
      bf16x8 af[4], bfr[4];
#pragma unroll
      for (int i = 0; i < 4; ++i) {
        int row = wm + i * 16 + lane16;
        int c = (kk * 4 + quad) ^ (row & 7);
        af[i] = *(const bf16x8*)(ldsA + row * 64 + c * 8);
      }
#pragma unroll
      for (int j = 0; j < 4; ++j) {
        int row = wn + j * 16 + lane16;
        int c = (kk * 4 + quad) ^ (row & 7);
        bfr[j] = *(const bf16x8*)(ldsB + row * 64 + c * 8);
      }
#pragma unroll
      for (int i = 0; i < 4; ++i)
#pragma unroll
        for (int j = 0; j < 4; ++j)
          acc[i][j] = __builtin_amdgcn_mfma_f32_16x16x32_bf16(af[i], bfr[j], acc[i][j], 0, 0, 0);
    }
    __syncthreads();
  }

  if (MODE == 0 && (int)(n0 >> 10) == 2) {
    // V path: bias + transpose via LDS, then 128B-contiguous stores to (bh,d,s).
#pragma unroll
    for (int j = 0; j < 4; ++j) {
      int lcol = wn + j * 16 + lane16;
      float bvj = bias2[(int)(n0 - 2048) + lcol];
#pragma unroll
      for (int i = 0; i < 4; ++i)
#pragma unroll
        for (int r = 0; r < 4; ++r) {
          int lrow = wm + i * 16 + quad * 4 + r;
          lds[lcol * 136 + lrow] = f2bf(acc[i][j][r] + bvj);
        }
    }
    __syncthreads();
    int lcol = tid >> 1, seg = tid & 1;
    int cc = (int)(n0 - 2048) + lcol;
    int head = cc >> 6, d = cc & 63;
    int bI = (int)(m0 >> 11), s0 = (int)(m0 & 2047);
    u16* dst = v_out + ((long)(bI * 16 + head) * 64 + d) * 2048 + s0 + seg * 64;
    const u16* s = lds + lcol * 136 + seg * 64;
#pragma unroll
    for (int c2 = 0; c2 < 8; ++c2) ((uint4*)dst)[c2] = ((const uint4*)s)[c2];
    return;
  }

  u16* pp = nullptr;
  if (MODE == 1) pp = blockIdx.z == 0 ? (u16*)outp : q_out;

#pragma unroll
  for (int j = 0; j < 4; ++j) {
    int col = (int)n0 + wn + j * 16 + lane16;
#pragma unroll
    for (int i = 0; i < 4; ++i) {
#pragma unroll
      for (int r = 0; r < 4; ++r) {
        int row = (int)m0 + wm + i * 16 + quad * 4 + r;
        float val = acc[i][j][r];
        if (MODE == 0) {
          int which = col >> 10, cc = col & 1023;
          float vv = val + (which == 0 ? bias0[cc] : bias1[cc]);
          int bb = row >> 11, sS = row & 2047, head = cc >> 6, d = cc & 63;
          long bh = (long)bb * 16 + head;
          if (which == 0) {
            q_out[(bh * 2048 + sS) * 64 + d] = f2bf(vv * 0.18033688f);  // 1/8 * log2(e)
          } else {
            k_out[(bh * 2048 + sS) * 64 + d] = f2bf(vv);
          }
        } else if (MODE == 1) {
          pp[(long)row * N + col] = f2bf(val);
        } else if (MODE == 2) {
          ((u16*)outp)[(long)row * N + col] = f2bf(fmaxf(val + bias0[col], 0.0f));
        }
      }
    }
  }
}

// -------- flash attention: 128-q blocks, 32 q/wave, key-split over gridDim.z --------
// Fixed-offset exp2 softmax => partials combine linearly: each z writes UNNORMALIZED
// O (bf16, ctx layout) + l (fp32, [z][bh][s]); attn_combine does ctx = sum(O)/sum(l).
// R5 LDS layout (~50KB -> 3 blocks/CU): P of waves 0/1 aliases ldsK (mid barrier),
// waves 2/3 dedicated. gridDim.z==3 -> key ranges 768/640/640 (1536 blocks = 2 full
// rounds at 3/CU); z==2 -> 1024/1024.
#define FA_C0 28.854239f  // 20 * log2(e) safety offset; scores |S|<~4 << 20
__global__ __launch_bounds__(256) void flash_attn(const u16* __restrict__ q,
                                                  const u16* __restrict__ k,
                                                  const u16* __restrict__ v,
                                                  const int* __restrict__ mask,
                                                  u16* __restrict__ o0,
                                                  u16* __restrict__ o1,
                                                  u16* __restrict__ o2,
                                                  float* __restrict__ lpart) {
  const int bh = blockIdx.y;
  const int b = bh >> 4, h = bh & 15;
  const int q0 = blockIdx.x * 128;
  const int z = blockIdx.z;
  const int tid = threadIdx.x;
  const int wave = tid >> 6, lane = tid & 63;
  const int lane16 = lane & 15, quad = lane >> 4;

  const u16* qp = q + (long)bh * 2048 * 64;
  const u16* kp = k + (long)bh * 2048 * 64;
  const u16* vp = v + (long)bh * 64 * 2048;
  const int* mp = mask + b * 2048;
  u16* op = z == 0 ? o0 : (z == 1 ? o1 : o2);

  int kbeg, ktiles;
  if (gridDim.z == 3) {
    kbeg = (z == 0) ? 0 : 768 + (z - 1) * 640;
    ktiles = (z == 0) ? 6 : 5;
  } else {
    kbeg = z * 1024;
    ktiles = 8;
  }

  __shared__ __align__(16) u16 ldsK[128 * 64];    // 16KB; P of waves 0/1 aliases
  __shared__ __align__(16) u16 ldsVT[64 * 128];   // 16KB
  __shared__ __align__(16) u16 ldsP23[2 * 4096];  // 16KB; P of waves 2/3
  __shared__ __align__(16) float ldsMask[128];
  __shared__ int ldsFlag[2];
  u16* myP = (wave < 2) ? (ldsK + wave * 4096) : (ldsP23 + (wave - 2) * 4096);

  bf16x8 qf[2][2];
#pragma unroll
  for (int g = 0; g < 2; ++g) {
    const long qrow = q0 + wave * 32 + g * 16 + lane16;
    qf[g][0] = *(const bf16x8*)(qp + qrow * 64 + quad * 8);
    qf[g][1] = *(const bf16x8*)(qp + qrow * 64 + 32 + quad * 8);
  }

  const f32x4 fzero = {0.f, 0.f, 0.f, 0.f};
  const f32x4 cC0 = {-FA_C0, -FA_C0, -FA_C0, -FA_C0};
  float l_loc[2] = {0.f, 0.f};
  f32x4 o_acc[2][4];
#pragma unroll
  for (int g = 0; g < 2; ++g)
#pragma unroll
    for (int j = 0; j < 4; ++j) o_acc[g][j] = fzero;

  const int xorm = (lane16 & 7) << 2;  // P chunk swizzle per q-row
  u16* const pw0 = myP + lane16 * 128;         // P write base, g=0
  u16* const pw1 = myP + (16 + lane16) * 128;  // g=1

  for (int it = 0; it < ktiles; ++it) {
    const int kt = kbeg + it * 128;
    stage128x64(kp, kt, 0, 64, ldsK, wave, lane);
    stage64x128(vp, kt, 2048, ldsVT, wave, lane);
    if (tid < 128) {
      int mv = mp[kt + tid];
      ldsMask[tid] = (mv == 0) ? -1.0e9f : 0.0f;
      unsigned long long bal = __ballot(mv != 0);
      if ((tid & 63) == 0) ldsFlag[tid >> 6] = (bal == ~0ull) ? 1 : 0;
    }
    __syncthreads();
    const bool allv = (ldsFlag[0] & ldsFlag[1]) != 0;

    // S^T = K @ Q^T  (128 keys x 32 q per wave); C-init = -C0, mask added only if !allv
    f32x4 s_acc[8][2];
#pragma unroll
    for (int j = 0; j < 8; ++j) {
      int row = j * 16 + lane16;
      int c0i = quad ^ (row & 7);
      int c1i = (4 + quad) ^ (row & 7);
      bf16x8 kf0 = *(const bf16x8*)(ldsK + row * 64 + c0i * 8);
      bf16x8 kf1 = *(const bf16x8*)(ldsK + row * 64 + c1i * 8);
#pragma unroll
      for (int g = 0; g < 2; ++g) {
        f32x4 sa = __builtin_amdgcn_mfma_f32_16x16x32_bf16(kf0, qf[g][0], cC0, 0, 0, 0);
        sa = __builtin_amdgcn_mfma_f32_16x16x32_bf16(kf1, qf[g][1], sa, 0, 0, 0);
        s_acc[j][g] = sa;
      }
    }
    __syncthreads();  // all waves' K reads done; waves 0/1 may overwrite ldsK with P

    // p = 2^s: pack 2x v_perm + 1 ds_write_b64 per (j,g)
#pragma unroll
    for (int j = 0; j < 8; ++j) {
      int cw = ((4 * j + quad) ^ xorm) * 4;
#pragma unroll
      for (int g = 0; g < 2; ++g) {
        f32x4 sa = s_acc[j][g];
        if (!allv) {
          f32x4 mk = *(const f32x4*)(ldsMask + j * 16 + quad * 4);
          sa = sa + mk;
        }
        float p0 = __builtin_exp2f(sa[0]);
        float p1 = __builtin_exp2f(sa[1]);
        float p2 = __builtin_exp2f(sa[2]);
        float p3 = __builtin_exp2f(sa[3]);
        l_loc[g] += (p0 + p1) + (p2 + p3);
        uint2 pk;
        pk.x = __builtin_amdgcn_perm(fbits(p1), fbits(p0), 0x07060302u);  // bf16 trunc pair
        pk.y = __builtin_amdgcn_perm(fbits(p3), fbits(p2), 0x07060302u);
        *(uint2*)((g ? pw1 : pw0) + cw) = pk;
      }
    }
    // O += P @ V (myP wave-private; in-wave write->read ordering only)
#pragma unroll
    for (int kk = 0; kk < 4; ++kk) {
      int cr = ((8 * kk + 2 * quad) ^ xorm) * 4;
      bf16x8 pf0 = *(const bf16x8*)(pw0 + cr);
      bf16x8 pf1 = *(const bf16x8*)(pw1 + cr);
#pragma unroll
      for (int jj = 0; jj < 4; ++jj) {
        int row = jj * 16 + lane16;
        int cv = (kk * 4 + quad) ^ (row & 15);
        bf16x8 vf = *(const bf16x8*)(ldsVT + row * 128 + cv * 8);
        o_acc[0][jj] = __builtin_amdgcn_mfma_f32_16x16x32_bf16(pf0, vf, o_acc[0][jj], 0, 0, 0);
        o_acc[1][jj] = __builtin_amdgcn_mfma_f32_16x16x32_bf16(pf1, vf, o_acc[1][jj], 0, 0, 0);
      }
    }
    __syncthreads();  // P(aliased)/VT reads done before next stage overwrites
  }

  // l: sum across quads -> full per-q sum in every lane of that column; quad 0 writes
#pragma unroll
  for (int g = 0; g < 2; ++g) {
    float l = l_loc[g];
#pragma unroll
    for (int off = 16; off < 64; off <<= 1) l += __shfl_xor(l, off);
    if (quad == 0)
      lpart[z * 65536 + bh * 2048 + (q0 + wave * 32 + g * 16 + lane16)] = l;
  }

  // unnormalized O partial, ctx layout
#pragma unroll
  for (int g = 0; g < 2; ++g)
#pragma unroll
    for (int jj = 0; jj < 4; ++jj)
#pragma unroll
      for (int r = 0; r < 4; ++r) {
        int sg = q0 + wave * 32 + g * 16 + quad * 4 + r;
        int d = jj * 16 + lane16;
        op[((long)b * 2048 + sg) * 1024 + h * 64 + d] = f2bf(o_acc[g][jj][r]);
      }
}

// ctx = (O0 + O1 [+ O2]) / (l0 + l1 [+ l2]); in-place safe for o0 == ctx.
template <int NS>
__global__ __launch_bounds__(256) void attn_combine(const u16* __restrict__ o0,
                                                    const u16* __restrict__ o1,
                                                    const u16* __restrict__ o2,
                                                    const float* __restrict__ lp,
                                                    u16* __restrict__ ctx) {
  int row = blockIdx.x, t = threadIdx.x;  // row = b*2048+s
  int b = row >> 11, s = row & 2047;
  int head = t >> 4;  // 4 cols/thread, 64 cols/head
  int li = (b * 16 + head) * 2048 + s;
  float l = lp[li] + lp[65536 + li];
  if (NS == 3) l += lp[2 * 65536 + li];
  float inv = 1.0f / l;
  long base = (long)row * 1024;
  ushort4 a = ((const ushort4*)(o0 + base))[t];
  ushort4 c = ((const ushort4*)(o1 + base))[t];
  float4 o;
  o.x = bf2f(a.x) + bf2f(c.x);
  o.y = bf2f(a.y) + bf2f(c.y);
  o.z = bf2f(a.z) + bf2f(c.z);
  o.w = bf2f(a.w) + bf2f(c.w);
  if (NS == 3) {
    ushort4 d = ((const ushort4*)(o2 + base))[t];
    o.x += bf2f(d.x); o.y += bf2f(d.y); o.z += bf2f(d.z); o.w += bf2f(d.w);
  }
  union { unsigned long long u64; u16 hh[4]; } pk;
  pk.hh[0] = f2bf(o.x * inv);
  pk.hh[1] = f2bf(o.y * inv);
  pk.hh[2] = f2bf(o.z * inv);
  pk.hh[3] = f2bf(o.w * inv);
  *(unsigned long long*)(ctx + base + t * 4) = pk.u64;
}

extern "C" void kernel_launch(void* const* d_in, const int* in_sizes, int n_in, void* d_out,
                              int out_size, void* d_ws, size_t ws_size, hipStream_t stream) {
  (void)in_sizes; (void)n_in; (void)out_size;
  const float* x  = (const float*)d_in[0];
  const int* mask = (const int*)d_in[1];
  const float* wq = (const float*)d_in[2];
  const float* wk = (const float*)d_in[3];
  const float* wv = (const float*)d_in[4];
  const float* wo = (const float*)d_in[5];
  const float* bq = (const float*)d_in[6];
  const float* bk = (const float*)d_in[7];
  const float* bv = (const float*)d_in[8];
  const float* bo = (const float*)d_in[9];
  const float* w1 = (const float*)d_in[10];
  const float* b1 = (const float*)d_in[11];
  const float* w2 = (const float*)d_in[12];
  const float* b2 = (const float*)d_in[13];
  const float* ln1_g = (const float*)d_in[14];
  const float* ln1_b = (const float*)d_in[15];
  const float* ln2_g = (const float*)d_in[16];
  const float* ln2_b = (const float*)d_in[17];
  float* out = (float*)d_out;

  u16* ws = (u16*)d_ws;
  u16* wqkvT = ws;                      // [0,3M) u16; lpart (768KB) aliases during attn
  u16* woT = wqkvT + 3072 * 1024;       // [3M,4M)
  u16* w1T = woT + 1024 * 1024;         // [4M,8M)
  u16* w2T = w1T + 4096 * 1024;         // [8M,12M)
  u16* h   = w2T + 4096 * 1024;         // [12M,16M)  LN1 out; O-partial z1; LN2 out
  u16* qb  = h + 4096 * 1024;           // [16M,20M)  Q; WO partial0
  u16* kb  = qb + 4096 * 1024;          // [20M,24M)  K; WO partial1
  u16* vb  = kb + 4096 * 1024;          // [24M,28M)  V^T
  u16* ctx = vb + 4096 * 1024;          // [28M,32M)  O-partial z0; combined ctx
  u16* ffh = qb;                        // [16M,32M)  4096x4096 relu acts (qb..ctx dead)
  u16* f2p0 = ws;                       // FFN2 partial0 (wqkvT+woT dead by then)
  u16* f2p1 = w1T;                      // FFN2 partial1 (w1T dead after FFN1)
  u16* opart2 = ws + (size_t)32 * 1024 * 1024;  // [32M,36.2M) third O partial (if room)
  float* lpart = (float*)ws;            // 3*65536 fp32 over dead wqkvT region

  // third partial needs (32M + 4M) u16 * 2B + slack
  const int nsplit = (ws_size >= (size_t)76 * 1024 * 1024) ? 3 : 2;

  // one launch: wq/wk/wv/wo/w1/w2 transposes + LN1
  prep<<<16384, 256, 0, stream>>>(wq, wk, wv, wo, w1, w2, x, ln1_g, ln1_b,
                                  wqkvT, w1T, w2T, h);

  gemm_bt<0><<<dim3(24, 32), 256, 0, stream>>>(h, wqkvT, 4096, 3072, 1024, nullptr, bq, bk, bv,
                                               qb, kb, vb);

  // key-split flash: unnormalized O partials (z0->ctx, z1->h, z2->opart2) + l partials
  flash_attn<<<dim3(16, 32, nsplit), 256, 0, stream>>>(qb, kb, vb, mask, ctx, h, opart2, lpart);
  if (nsplit == 3)
    attn_combine<3><<<4096, 256, 0, stream>>>(ctx, h, opart2, lpart, ctx);
  else
    attn_combine<2><<<4096, 256, 0, stream>>>(ctx, h, nullptr, lpart, ctx);

  // WO: split-K x2, bf16 partials into qb (z0) / kb (z1), both dead after attention
  gemm_bt<1><<<dim3(8, 32, 2), 256, 0, stream>>>(ctx, woT, 4096, 1024, 1024, qb, nullptr,
                                                 nullptr, nullptr, kb, nullptr, nullptr);

  // fused: y = x + bo + P0 + P1 -> out (fp32 residual) and h = LN2(y) bf16
  ln_fuse<<<4096, 256, 0, stream>>>(x, bo, qb, kb, ln2_g, ln2_b, out, h);

  gemm_bt<2><<<dim3(32, 32), 256, 0, stream>>>(h, w1T, 4096, 4096, 1024, ffh, b1, nullptr,
                                               nullptr, nullptr, nullptr, nullptr);

  // FFN2: split-K x2, bf16 partials into dead weight regions
  gemm_bt<1><<<dim3(8, 32, 2), 256, 0, stream>>>(ffh, w2T, 4096, 1024, 4096, f2p0, nullptr,
                                                 nullptr, nullptr, f2p1, nullptr, nullptr);

  final_add<<<4096, 256, 0, stream>>>(out, b2, f2p0, f2p1);
}

// Round 8
// 363.191 us; speedup vs baseline: 1.1426x; 1.1426x over previous
//
#include <hip/hip_runtime.h>

typedef unsigned short u16;
typedef unsigned int u32;
typedef __attribute__((ext_vector_type(8))) short bf16x8;
typedef __attribute__((ext_vector_type(4))) float f32x4;

__device__ __forceinline__ u16 f2bf(float f) {
  union { float f; unsigned int u; } x;
  x.f = f;
  unsigned int r = x.u + 0x7fffu + ((x.u >> 16) & 1u);
  return (u16)(r >> 16);
}

__device__ __forceinline__ float bf2f(u16 v) {
  union { unsigned int u; float f; } x;
  x.u = ((unsigned int)v) << 16;
  return x.f;
}

__device__ __forceinline__ u32 fbits(float f) {
  union { float f; u32 u; } x; x.f = f; return x.u;
}

__device__ __forceinline__ void async16(const u16* g, u16* l) {
  __builtin_amdgcn_global_load_lds((const __attribute__((address_space(1))) void*)g,
                                   (__attribute__((address_space(3))) void*)l, 16, 0, 0);
}

// Stage 128 rows x 64 cols bf16 tile. LDS slot s: row=s>>3, stored chunk (s&7)
// holds global 16B chunk c = (s&7) ^ (row&7)  (XOR swizzle -> conflict-free b128 reads).
__device__ __forceinline__ void stage128x64(const u16* __restrict__ src, long row0, int k0,
                                            int ld, u16* lds, int wave, int lane) {
#pragma unroll
  for (int r = 0; r < 4; ++r) {
    int s = r * 256 + wave * 64 + lane;
    int row = s >> 3;
    int c = (s & 7) ^ (row & 7);
    async16(src + (row0 + row) * (long)ld + k0 + c * 8, lds + (r * 256 + wave * 64) * 8);
  }
}

// Stage 64 rows x 128 cols (V^T tile): 16 chunks/row, swizzle c = (s&15)^(row&15).
__device__ __forceinline__ void stage64x128(const u16* __restrict__ src, int col0, int ld,
                                            u16* lds, int wave, int lane) {
#pragma unroll
  for (int r = 0; r < 4; ++r) {
    int s = r * 256 + wave * 64 + lane;
    int row = s >> 4;
    int c = (s & 15) ^ (row & 15);
    async16(src + (long)row * ld + col0 + c * 8, lds + (r * 256 + wave * 64) * 8);
  }
}

// ---------------- LayerNorm core (torch-style: unbiased std, /(std+eps)) ----------------
__device__ __forceinline__ void ln_core(float4 v, const float* g, const float* b, int t,
                                        u16* outrow) {
  float s = v.x + v.y + v.z + v.w;
  float ss = v.x * v.x + v.y * v.y + v.z * v.z + v.w * v.w;
#pragma unroll
  for (int off = 32; off; off >>= 1) {
    s += __shfl_xor(s, off);
    ss += __shfl_xor(ss, off);
  }
  __shared__ float red[8];
  int wave = t >> 6, lane = t & 63;
  if (lane == 0) { red[wave] = s; red[wave + 4] = ss; }
  __syncthreads();
  float tot = red[0] + red[1] + red[2] + red[3];
  float tots = red[4] + red[5] + red[6] + red[7];
  float mean = tot * (1.0f / 1024.0f);
  float var = (tots - 1024.0f * mean * mean) * (1.0f / 1023.0f);
  var = fmaxf(var, 0.0f);
  float inv = 1.0f / (sqrtf(var) + 1e-6f);
  float4 gv = ((const float4*)g)[t];
  float4 bv = ((const float4*)b)[t];
  union { unsigned long long u64; u16 h[4]; } o;
  o.h[0] = f2bf(gv.x * (v.x - mean) * inv + bv.x);
  o.h[1] = f2bf(gv.y * (v.y - mean) * inv + bv.y);
  o.h[2] = f2bf(gv.z * (v.z - mean) * inv + bv.z);
  o.h[3] = f2bf(gv.w * (v.w - mean) * inv + bv.w);
  *(unsigned long long*)(outrow + t * 4) = o.u64;
}

// ---------------- prep: all weight transposes + LN1 in ONE launch ----------------
// 16384 blocks: [0,4k) wq/wk/wv/wo transpose; [4k,8k) LN1; [8k,12k) w1; [12k,16k) w2.
__global__ __launch_bounds__(256) void prep(const float* __restrict__ wq,
                                            const float* __restrict__ wk,
                                            const float* __restrict__ wv,
                                            const float* __restrict__ wo,
                                            const float* __restrict__ w1,
                                            const float* __restrict__ w2,
                                            const float* __restrict__ x,
                                            const float* __restrict__ ln1_g,
                                            const float* __restrict__ ln1_b,
                                            u16* __restrict__ wqkvT,  // + woT contiguous
                                            u16* __restrict__ w1T,
                                            u16* __restrict__ w2T,
                                            u16* __restrict__ hout) {
  const int bid = blockIdx.x;
  const int part = bid >> 12;
  const int local = bid & 4095;
  const int t = threadIdx.x;
  if (part == 1) {
    float4 v = ((const float4*)(x + (long)local * 1024))[t];
    ln_core(v, ln1_g, ln1_b, t, hout + (long)local * 1024);
    return;
  }
  __shared__ float tile[32][33];
  const float* src; u16* dst; int C, R, bx, by;
  if (part == 0) {
    int sub = local >> 10;
    src = sub == 0 ? wq : (sub == 1 ? wk : (sub == 2 ? wv : wo));
    dst = wqkvT + (long)sub * 1024 * 1024;
    C = 1024; R = 1024; bx = local & 31; by = (local >> 5) & 31;
  } else if (part == 2) {
    src = w1; dst = w1T; C = 4096; R = 1024; bx = local & 127; by = local >> 7;
  } else {
    src = w2; dst = w2T; C = 1024; R = 4096; bx = local & 31; by = local >> 5;
  }
  int c0 = bx * 32, r0 = by * 32;
  int tx = t & 31, ty = t >> 5;
#pragma unroll
  for (int i = 0; i < 32; i += 8)
    tile[ty + i][tx] = src[(long)(r0 + ty + i) * C + c0 + tx];
  __syncthreads();
#pragma unroll
  for (int i = 0; i < 32; i += 8)
    dst[(long)(c0 + ty + i) * R + r0 + tx] = f2bf(tile[tx][ty + i]);
}

// y = x + bres + P0 + P1 (WO split-K2 reduce); write y fp32 and LN2(y) bf16.
__global__ __launch_bounds__(256) void ln_fuse(const float* __restrict__ x,
                                               const float* __restrict__ bres,
                                               const u16* __restrict__ p0,
                                               const u16* __restrict__ p1,
                                               const float* __restrict__ g,
                                               const float* __restrict__ b,
                                               float* __restrict__ yout,
                                               u16* __restrict__ hout) {
  int row = blockIdx.x, t = threadIdx.x;
  long base = (long)row * 1024;
  float4 xv = ((const float4*)(x + base))[t];
  float4 bo = ((const float4*)bres)[t];
  ushort4 a = ((const ushort4*)(p0 + base))[t];
  ushort4 c = ((const ushort4*)(p1 + base))[t];
  float4 y;
  y.x = xv.x + bo.x + bf2f(a.x) + bf2f(c.x);
  y.y = xv.y + bo.y + bf2f(a.y) + bf2f(c.y);
  y.z = xv.z + bo.z + bf2f(a.z) + bf2f(c.z);
  y.w = xv.w + bo.w + bf2f(a.w) + bf2f(c.w);
  ((float4*)(yout + base))[t] = y;
  ln_core(y, g, b, t, hout + base);
}

// out += b2 + Q0 + Q1 (FFN2 split-K2 reduce + bias, in-place on residual)
__global__ __launch_bounds__(256) void final_add(float* __restrict__ out,
                                                 const float* __restrict__ b2,
                                                 const u16* __restrict__ p0,
                                                 const u16* __restrict__ p1) {
  int row = blockIdx.x, t = threadIdx.x;
  long base = (long)row * 1024;
  float4 o = ((float4*)(out + base))[t];
  float4 bb = ((const float4*)b2)[t];
  ushort4 a = ((const ushort4*)(p0 + base))[t];
  ushort4 c = ((const ushort4*)(p1 + base))[t];
  o.x += bb.x + bf2f(a.x) + bf2f(c.x);
  o.y += bb.y + bf2f(a.y) + bf2f(c.y);
  o.z += bb.z + bf2f(a.z) + bf2f(c.z);
  o.w += bb.w + bf2f(a.w) + bf2f(c.w);
  ((float4*)(out + base))[t] = o;
}

// ---------------- bf16 GEMM: C = A(MxK) @ Bt(NxK)^T, templated epilogue ----------------
// MODE 0: QKV scatter (+bias; q *= 0.125*log2e; q/k direct, v via LDS transpose -> (bh,d,s))
// MODE 1: bf16 partial store; pointer per z: z0->outp, z1->q_out
// MODE 2: out bf16 = relu(acc + bias0)
template <int MODE>
__global__ __launch_bounds__(256) void gemm_bt(const u16* __restrict__ A,
                                               const u16* __restrict__ Bt, int M, int N, int K,
                                               void* __restrict__ outp,
                                               const float* __restrict__ bias0,
                                               const float* __restrict__ bias1,
                                               const float* __restrict__ bias2,
                                               u16* __restrict__ q_out, u16* __restrict__ k_out,
                                               u16* __restrict__ v_out) {
  __shared__ __align__(16) u16 lds[17408];  // A: [0,8192) B: [8192,16384); epi: 128x136
  u16* ldsA = lds;
  u16* ldsB = lds + 8192;
  const int tid = threadIdx.x;
  const int wave = tid >> 6, lane = tid & 63;
  const int lane16 = lane & 15, quad = lane >> 4;
  const int wm = (wave >> 1) * 64, wn = (wave & 1) * 64;
  const long m0 = (long)blockIdx.y * 128;
  const long n0 = (long)blockIdx.x * 128;
  const int kLen = K / gridDim.z;
  const int kBeg = blockIdx.z * kLen;

  const f32x4 fzero = {0.f, 0.f, 0.f, 0.f};
  f32x4 acc[4][4];
#pragma unroll
  for (int i = 0; i < 4; ++i)
#pragma unroll
    for (int j = 0; j < 4; ++j) acc[i][j] = fzero;

  for (int k0 = kBeg; k0 < kBeg + kLen; k0 += 64) {
    stage128x64(A, m0, k0, K, ldsA, wave, lane);
    stage128x64(Bt, n0, k0, K, ldsB, wave, lane);
    __syncthreads();
#pragma unroll
    for (int kk = 0; kk < 2; ++kk) {
      bf16x8 af[4], bfr[4];
#pragma unroll
      for (int i = 0; i < 4; ++i) {
        int row = wm + i * 16 + lane16;
        int c = (kk * 4 + quad) ^ (row & 7);
        af[i] = *(const bf16x8*)(ldsA + row * 64 + c * 8);
      }
#pragma unroll
      for (int j = 0; j < 4; ++j) {
        int row = wn + j * 16 + lane16;
        int c = (kk * 4 + quad) ^ (row & 7);
        bfr[j] = *(const bf16x8*)(ldsB + row * 64 + c * 8);
      }
#pragma unroll
      for (int i = 0; i < 4; ++i)
#pragma unroll
        for (int j = 0; j < 4; ++j)
          acc[i][j] = __builtin_amdgcn_mfma_f32_16x16x32_bf16(af[i], bfr[j], acc[i][j], 0, 0, 0);
    }
    __syncthreads();
  }

  if (MODE == 0 && (int)(n0 >> 10) == 2) {
    // V path: bias + transpose via LDS, then 128B-contiguous stores to (bh,d,s).
#pragma unroll
    for (int j = 0; j < 4; ++j) {
      int lcol = wn + j * 16 + lane16;
      float bvj = bias2[(int)(n0 - 2048) + lcol];
#pragma unroll
      for (int i = 0; i < 4; ++i)
#pragma unroll
        for (int r = 0; r < 4; ++r) {
          int lrow = wm + i * 16 + quad * 4 + r;
          lds[lcol * 136 + lrow] = f2bf(acc[i][j][r] + bvj);
        }
    }
    __syncthreads();
    int lcol = tid >> 1, seg = tid & 1;
    int cc = (int)(n0 - 2048) + lcol;
    int head = cc >> 6, d = cc & 63;
    int bI = (int)(m0 >> 11), s0 = (int)(m0 & 2047);
    u16* dst = v_out + ((long)(bI * 16 + head) * 64 + d) * 2048 + s0 + seg * 64;
    const u16* s = lds + lcol * 136 + seg * 64;
#pragma unroll
    for (int c2 = 0; c2 < 8; ++c2) ((uint4*)dst)[c2] = ((const uint4*)s)[c2];
    return;
  }

  u16* pp = nullptr;
  if (MODE == 1) pp = blockIdx.z == 0 ? (u16*)outp : q_out;

#pragma unroll
  for (int j = 0; j < 4; ++j) {
    int col = (int)n0 + wn + j * 16 + lane16;
#pragma unroll
    for (int i = 0; i < 4; ++i) {
#pragma unroll
      for (int r = 0; r < 4; ++r) {
        int row = (int)m0 + wm + i * 16 + quad * 4 + r;
        float val = acc[i][j][r];
        if (MODE == 0) {
          int which = col >> 10, cc = col & 1023;
          float vv = val + (which == 0 ? bias0[cc] : bias1[cc]);
          int bb = row >> 11, sS = row & 2047, head = cc >> 6, d = cc & 63;
          long bh = (long)bb * 16 + head;
          if (which == 0) {
            q_out[(bh * 2048 + sS) * 64 + d] = f2bf(vv * 0.18033688f);  // 1/8 * log2(e)
          } else {
            k_out[(bh * 2048 + sS) * 64 + d] = f2bf(vv);
          }
        } else if (MODE == 1) {
          pp[(long)row * N + col] = f2bf(val);
        } else if (MODE == 2) {
          ((u16*)outp)[(long)row * N + col] = f2bf(fmaxf(val + bias0[col], 0.0f));
        }
      }
    }
  }
}

// -------- flash attention: 128-q blocks, 32 q/wave (best measured config: R5 layout) --------
// grid (16 q-tiles, 32 bh), XCD-remapped so all 16 q-tiles of one bh share an XCD L2.
// S^T = mfma(A=K,B=Q): lane holds 4 consecutive keys -> exp2 + v_perm pack -> ds_write_b64.
// P of waves 0/1 aliases ldsK (barrier between S-compute and pack); waves 2/3 dedicated.
// LDS ~50KB -> 3 blocks/CU. Mask folded post-MFMA only on !allv tiles (never for all-ones).
#define FA_C0 28.854239f  // 20 * log2(e) safety offset; scores |S|<~4 << 20
__global__ __launch_bounds__(256) void flash_attn(const u16* __restrict__ q,
                                                  const u16* __restrict__ k,
                                                  const u16* __restrict__ v,
                                                  const int* __restrict__ mask,
                                                  u16* __restrict__ ctx) {
  // XCD-aware remap: flat id -> (bh, qtile) s.t. same bh stays on one XCD (id&7).
  const int fid = blockIdx.y * 16 + blockIdx.x;
  const int xcd = fid & 7, slot = fid >> 3;
  const int bh = xcd * 4 + (slot >> 4);
  const int q0 = (slot & 15) * 128;
  const int b = bh >> 4, h = bh & 15;
  const int tid = threadIdx.x;
  const int wave = tid >> 6, lane = tid & 63;
  const int lane16 = lane & 15, quad = lane >> 4;

  const u16* qp = q + (long)bh * 2048 * 64;
  const u16* kp = k + (long)bh * 2048 * 64;
  const u16* vp = v + (long)bh * 64 * 2048;
  const int* mp = mask + b * 2048;

  __shared__ __align__(16) u16 ldsK[128 * 64];    // 16KB; P of waves 0/1 aliases
  __shared__ __align__(16) u16 ldsVT[64 * 128];   // 16KB
  __shared__ __align__(16) u16 ldsP23[2 * 4096];  // 16KB; P of waves 2/3
  __shared__ __align__(16) float ldsMask[128];
  __shared__ int ldsFlag[2];
  u16* myP = (wave < 2) ? (ldsK + wave * 4096) : (ldsP23 + (wave - 2) * 4096);

  bf16x8 qf[2][2];
#pragma unroll
  for (int g = 0; g < 2; ++g) {
    const long qrow = q0 + wave * 32 + g * 16 + lane16;
    qf[g][0] = *(const bf16x8*)(qp + qrow * 64 + quad * 8);
    qf[g][1] = *(const bf16x8*)(qp + qrow * 64 + 32 + quad * 8);
  }

  const f32x4 fzero = {0.f, 0.f, 0.f, 0.f};
  const f32x4 cC0 = {-FA_C0, -FA_C0, -FA_C0, -FA_C0};
  float l_loc[2] = {0.f, 0.f};
  f32x4 o_acc[2][4];
#pragma unroll
  for (int g = 0; g < 2; ++g)
#pragma unroll
    for (int j = 0; j < 4; ++j) o_acc[g][j] = fzero;

  const int xorm = (lane16 & 7) << 2;  // P chunk swizzle per q-row
  u16* const pw0 = myP + lane16 * 128;         // P write base, g=0
  u16* const pw1 = myP + (16 + lane16) * 128;  // g=1

  for (int kt = 0; kt < 2048; kt += 128) {
    stage128x64(kp, kt, 0, 64, ldsK, wave, lane);
    stage64x128(vp, kt, 2048, ldsVT, wave, lane);
    if (tid < 128) {
      int mv = mp[kt + tid];
      ldsMask[tid] = (mv == 0) ? -1.0e9f : 0.0f;
      unsigned long long bal = __ballot(mv != 0);
      if ((tid & 63) == 0) ldsFlag[tid >> 6] = (bal == ~0ull) ? 1 : 0;
    }
    __syncthreads();
    const bool allv = (ldsFlag[0] & ldsFlag[1]) != 0;

    // S^T = K @ Q^T  (128 keys x 32 q per wave); C-init = -C0
    f32x4 s_acc[8][2];
#pragma unroll
    for (int j = 0; j < 8; ++j) {
      int row = j * 16 + lane16;
      int c0i = quad ^ (row & 7);
      int c1i = (4 + quad) ^ (row & 7);
      bf16x8 kf0 = *(const bf16x8*)(ldsK + row * 64 + c0i * 8);
      bf16x8 kf1 = *(const bf16x8*)(ldsK + row * 64 + c1i * 8);
#pragma unroll
      for (int g = 0; g < 2; ++g) {
        f32x4 sa = __builtin_amdgcn_mfma_f32_16x16x32_bf16(kf0, qf[g][0], cC0, 0, 0, 0);
        sa = __builtin_amdgcn_mfma_f32_16x16x32_bf16(kf1, qf[g][1], sa, 0, 0, 0);
        s_acc[j][g] = sa;
      }
    }
    __syncthreads();  // all waves' K reads done; waves 0/1 may overwrite ldsK with P

    // p = 2^s (mask deferred: only on !allv tiles): pack 2x v_perm + 1 ds_write_b64
#pragma unroll
    for (int j = 0; j < 8; ++j) {
      int cw = ((4 * j + quad) ^ xorm) * 4;
#pragma unroll
      for (int g = 0; g < 2; ++g) {
        f32x4 sa = s_acc[j][g];
        if (!allv) {
          f32x4 mk = *(const f32x4*)(ldsMask + j * 16 + quad * 4);
          sa = sa + mk;
        }
        float p0 = __builtin_exp2f(sa[0]);
        float p1 = __builtin_exp2f(sa[1]);
        float p2 = __builtin_exp2f(sa[2]);
        float p3 = __builtin_exp2f(sa[3]);
        l_loc[g] += (p0 + p1) + (p2 + p3);
        uint2 pk;
        pk.x = __builtin_amdgcn_perm(fbits(p1), fbits(p0), 0x07060302u);  // bf16 trunc pair
        pk.y = __builtin_amdgcn_perm(fbits(p3), fbits(p2), 0x07060302u);
        *(uint2*)((g ? pw1 : pw0) + cw) = pk;
      }
    }
    // O += P @ V (myP wave-private; in-wave write->read ordering only)
#pragma unroll
    for (int kk = 0; kk < 4; ++kk) {
      int cr = ((8 * kk + 2 * quad) ^ xorm) * 4;
      bf16x8 pf0 = *(const bf16x8*)(pw0 + cr);
      bf16x8 pf1 = *(const bf16x8*)(pw1 + cr);
#pragma unroll
      for (int jj = 0; jj < 4; ++jj) {
        int row = jj * 16 + lane16;
        int cv = (kk * 4 + quad) ^ (row & 15);
        bf16x8 vf = *(const bf16x8*)(ldsVT + row * 128 + cv * 8);
        o_acc[0][jj] = __builtin_amdgcn_mfma_f32_16x16x32_bf16(pf0, vf, o_acc[0][jj], 0, 0, 0);
        o_acc[1][jj] = __builtin_amdgcn_mfma_f32_16x16x32_bf16(pf1, vf, o_acc[1][jj], 0, 0, 0);
      }
    }
    __syncthreads();  // P(aliased)/VT reads done before next stage overwrites
  }

  // l: sum across quads; broadcast per-o-row inverse
  float lr[2][4];
#pragma unroll
  for (int g = 0; g < 2; ++g) {
    float l = l_loc[g];
#pragma unroll
    for (int off = 16; off < 64; off <<= 1) l += __shfl_xor(l, off);
    float linv = 1.0f / l;  // valid for q = lane16 in every quad
#pragma unroll
    for (int r = 0; r < 4; ++r) lr[g][r] = __shfl(linv, quad * 4 + r);
  }

#pragma unroll
  for (int g = 0; g < 2; ++g)
#pragma unroll
    for (int jj = 0; jj < 4; ++jj)
#pragma unroll
      for (int r = 0; r < 4; ++r) {
        int sg = q0 + wave * 32 + g * 16 + quad * 4 + r;
        int d = jj * 16 + lane16;
        float val = o_acc[g][jj][r] * lr[g][r];
        ctx[((long)b * 2048 + sg) * 1024 + h * 64 + d] = f2bf(val);
      }
}

extern "C" void kernel_launch(void* const* d_in, const int* in_sizes, int n_in, void* d_out,
                              int out_size, void* d_ws, size_t ws_size, hipStream_t stream) {
  (void)in_sizes; (void)n_in; (void)out_size; (void)ws_size;
  const float* x  = (const float*)d_in[0];
  const int* mask = (const int*)d_in[1];
  const float* wq = (const float*)d_in[2];
  const float* wk = (const float*)d_in[3];
  const float* wv = (const float*)d_in[4];
  const float* wo = (const float*)d_in[5];
  const float* bq = (const float*)d_in[6];
  const float* bk = (const float*)d_in[7];
  const float* bv = (const float*)d_in[8];
  const float* bo = (const float*)d_in[9];
  const float* w1 = (const float*)d_in[10];
  const float* b1 = (const float*)d_in[11];
  const float* w2 = (const float*)d_in[12];
  const float* b2 = (const float*)d_in[13];
  const float* ln1_g = (const float*)d_in[14];
  const float* ln1_b = (const float*)d_in[15];
  const float* ln2_g = (const float*)d_in[16];
  const float* ln2_b = (const float*)d_in[17];
  float* out = (float*)d_out;

  u16* ws = (u16*)d_ws;
  u16* wqkvT = ws;                      // [0,3M) u16
  u16* woT = wqkvT + 3072 * 1024;       // [3M,4M)
  u16* w1T = woT + 1024 * 1024;         // [4M,8M)
  u16* w2T = w1T + 4096 * 1024;         // [8M,12M)
  u16* h   = w2T + 4096 * 1024;         // [12M,16M)  LN1 out; LN2 out
  u16* qb  = h + 4096 * 1024;           // [16M,20M)  Q; WO partial0
  u16* kb  = qb + 4096 * 1024;          // [20M,24M)  K; WO partial1
  u16* vb  = kb + 4096 * 1024;          // [24M,28M)  V^T
  u16* ctx = vb + 4096 * 1024;          // [28M,32M)
  u16* ffh = qb;                        // [16M,32M)  4096x4096 relu acts (qb..ctx dead)
  u16* f2p0 = ws;                       // FFN2 partial0 (wqkvT+woT dead by then)
  u16* f2p1 = w1T;                      // FFN2 partial1 (w1T dead after FFN1)

  // one launch: wq/wk/wv/wo/w1/w2 transposes + LN1
  prep<<<16384, 256, 0, stream>>>(wq, wk, wv, wo, w1, w2, x, ln1_g, ln1_b,
                                  wqkvT, w1T, w2T, h);

  gemm_bt<0><<<dim3(24, 32), 256, 0, stream>>>(h, wqkvT, 4096, 3072, 1024, nullptr, bq, bk, bv,
                                               qb, kb, vb);

  flash_attn<<<dim3(16, 32), 256, 0, stream>>>(qb, kb, vb, mask, ctx);

  // WO: split-K x2, bf16 partials into qb (z0) / kb (z1), both dead after attention
  gemm_bt<1><<<dim3(8, 32, 2), 256, 0, stream>>>(ctx, woT, 4096, 1024, 1024, qb, nullptr,
                                                 nullptr, nullptr, kb, nullptr, nullptr);

  // fused: y = x + bo + P0 + P1 -> out (fp32 residual) and h = LN2(y) bf16
  ln_fuse<<<4096, 256, 0, stream>>>(x, bo, qb, kb, ln2_g, ln2_b, out, h);

  gemm_bt<2><<<dim3(32, 32), 256, 0, stream>>>(h, w1T, 4096, 4096, 1024, ffh, b1, nullptr,
                                               nullptr, nullptr, nullptr, nullptr);

  // FFN2: split-K x2, bf16 partials into dead weight regions
  gemm_bt<1><<<dim3(8, 32, 2), 256, 0, stream>>>(ffh, w2T, 4096, 1024, 4096, f2p0, nullptr,
                                                 nullptr, nullptr, f2p1, nullptr, nullptr);

  final_add<<<4096, 256, 0, stream>>>(out, b2, f2p0, f2p1);
}